// Round 14
// baseline (130.201 us; speedup 1.0000x reference)
//
#include <hip/hip_runtime.h>
#include <stdint.h>

#define BB 2
#define HH 16
#define TT 2048
#define DD 64
#define NHASH 4
#define NHALF 32     // num_buckets/2
#define GCERT 0.00390625f   // certification gap: >=19x the worst-case f32-vs-f64 dot error

// ---------------- Phase 1: packed bucket words, f32-screen + f64-refine ----------------
// grid: BB*HH*(TT/64) = 1024 blocks x 256 threads (4 waves), 3 blocks/CU.
// wave = hash n; lane (tg=lane>>3, rg=lane&7) owns an 8-token x 4-r f32 acc tile.
// Decisions certified when top-2 gaps and the max-vs-(-min) margin all exceed GCERT;
// uncertain (incl. exact ties) (n,t) are recomputed in f64 from the intact LDS tiles.
// Certified + refined decisions reproduce the f64 pipeline (absmax 0, rounds 2-13).
__global__ __launch_bounds__(256, 3) void lsh_buckets_kernel(
    const float* __restrict__ hs,    // [BB, TT, HH*DD]
    const float* __restrict__ rot,   // [HH, DD, NHASH, NHALF]
    uint32_t* __restrict__ words)    // [BB*HH*TT]
{
    __shared__ uint32_t lds[12552];            // 49.03 KiB: tiles + bkt + unc
    float4* v4 = (float4*)lds;                 // [64 t][16 slots]      idx 0..4095
    float4* r4 = (float4*)(lds + 4096);        // [4 n][32 r][16 slots] idx 4096..12287
    // bkt: lds[12288..12543] = [4 n][64 t]; unc: lds[12544..12551] = [4 n][2]

    const int blk  = blockIdx.x;
    const int bh   = blk >> 5;        // / (TT/64)
    const int tblk = blk & 31;
    const int b    = bh >> 4;
    const int h    = bh & 15;
    const int t0   = tblk * 64;
    const int tid  = threadIdx.x;
    const int n    = tid >> 6;        // wave = hash
    const int lane = tid & 63;
    const int tg   = lane >> 3;       // token group (8 tokens)
    const int rg   = lane & 7;        // r group (4 r's)

    if (tid < 8) lds[12544 + tid] = 0;   // clear uncertainty bitmap

    // ---- stage v tile: [64 t][64 d] f32, slot = d4 ^ (t>>3) ----
    #pragma unroll
    for (int p = 0; p < 4; ++p) {
        const int k  = tid + p * 256;
        const int t  = k >> 4;
        const int d4 = k & 15;
        const float4 f = ((const float4*)(hs + ((size_t)(b * TT + t0 + t)) * (HH * DD) + h * DD))[d4];
        v4[t * 16 + (d4 ^ (t >> 3))] = f;
    }
    // ---- stage rot: [4 n][32 r][64 d] f32, slot = d4 ^ (r>>2) ----
    {
        const float* rh = rot + (size_t)h * (DD * NHASH * NHALF);
        float* rf = (float*)r4;
        #pragma unroll
        for (int p = 0; p < 32; ++p) {
            const int g  = tid + p * 256;   // d*128 + n*32 + r (coalesced)
            const int d  = g >> 7;
            const int nr = g & 127;
            const int nn = nr >> 5;
            const int r  = nr & 31;
            const int slot = (d >> 2) ^ (r >> 2);
            rf[((nn * 32 + r) * 16 + slot) * 4 + (d & 3)] = rh[g];
        }
    }
    __syncthreads();

    // ---- K loop: acc[i][j] f32 (t = tg*8+i, r = rg*4+j) ----
    float acc[8][4];
    #pragma unroll
    for (int i = 0; i < 8; ++i)
        #pragma unroll
        for (int j = 0; j < 4; ++j) acc[i][j] = 0.0f;

    const int vbase = tg * 8 * 16;
    const int rbase = (n * 32 + rg * 4) * 16;
    const int r0    = rg * 4;

    for (int s = 0; s < 16; ++s) {              // d = s*4 .. s*4+3
        float4 rd[4];
        #pragma unroll
        for (int j = 0; j < 4; ++j) rd[j] = r4[rbase + j * 16 + (s ^ rg)];
        #pragma unroll
        for (int i = 0; i < 8; ++i) {
            const float4 vf = v4[vbase + i * 16 + (s ^ tg)];
            #pragma unroll
            for (int j = 0; j < 4; ++j) {
                acc[i][j] += vf.x * rd[j].x;
                acc[i][j] += vf.y * rd[j].y;
                acc[i][j] += vf.z * rd[j].z;
                acc[i][j] += vf.w * rd[j].w;
            }
        }
    }

    // ---- epilogue: per-token top-2 max/min via lane-local + rg shfl-butterfly ----
    #pragma unroll
    for (int i = 0; i < 8; ++i) {
        float m1 = -INFINITY, m2 = -INFINITY; int i1 = 0;
        float n1 =  INFINITY, n2 =  INFINITY; int j1 = 0;
        #pragma unroll
        for (int j = 0; j < 4; ++j) {
            const float f = acc[i][j];
            const int   r = r0 + j;
            if (f > m1) { m2 = m1; m1 = f; i1 = r; } else if (f > m2) m2 = f;
            if (f < n1) { n2 = n1; n1 = f; j1 = r; } else if (f < n2) n2 = f;
        }
        #pragma unroll
        for (int off = 1; off < 8; off <<= 1) {   // merge the 8 rg groups (lane bits 0-2)
            const float pm1 = __shfl_xor(m1, off); const int pi1 = __shfl_xor(i1, off);
            const float pm2 = __shfl_xor(m2, off);
            const float pn1 = __shfl_xor(n1, off); const int pj1 = __shfl_xor(j1, off);
            const float pn2 = __shfl_xor(n2, off);
            if (pm1 > m1 || (pm1 == m1 && pi1 < i1)) { m2 = fmaxf(m1, pm2); m1 = pm1; i1 = pi1; }
            else                                     { m2 = fmaxf(m2, pm1); }
            if (pn1 < n1 || (pn1 == n1 && pj1 < j1)) { n2 = fminf(n1, pn2); n1 = pn1; j1 = pj1; }
            else                                     { n2 = fminf(n2, pn1); }
        }
        if (rg == 0) {
            const int t = tg * 8 + i;
            const bool cert = (m1 - m2 > GCERT) && (n2 - n1 > GCERT) && (fabsf(m1 + n1) > GCERT);
            lds[12288 + n * 64 + t] = (m1 >= -n1) ? (uint32_t)i1 : (uint32_t)(NHALF + j1);
            if (!cert)
                atomicOr(&lds[12544 + n * 2 + (t >> 5)], 1u << (t & 31));
        }
    }
    __syncthreads();

    // ---- refine: wave n recomputes its uncertain tokens in f64 (tiles intact) ----
    {
        uint32_t mlo = lds[12544 + n * 2];
        uint32_t mhi = lds[12544 + n * 2 + 1];
        const int r    = lane & 31;
        const int hsel = lane >> 5;
        const int rb2  = (n * 32 + r) * 16;
        const int rsw  = r >> 2;
        while (mlo | mhi) {
            int t;
            if (mlo) { t = __ffs(mlo) - 1;      mlo &= mlo - 1; }
            else     { t = 32 + __ffs(mhi) - 1; mhi &= mhi - 1; }
            double a0 = 0.0, a1 = 0.0;
            const int tb  = t * 16;
            const int tsw = t >> 3;
            #pragma unroll
            for (int c = 0; c < 8; ++c) {
                const int d4 = hsel * 8 + c;
                const float4 vf = v4[tb + (d4 ^ tsw)];
                const float4 rf = r4[rb2 + (d4 ^ rsw)];
                a0 += (double)vf.x * (double)rf.x;
                a1 += (double)vf.y * (double)rf.y;
                a0 += (double)vf.z * (double)rf.z;
                a1 += (double)vf.w * (double)rf.w;
            }
            double dsum = a0 + a1;
            dsum += __shfl_xor(dsum, 32);       // combine the two d-halves
            const float f = (float)dsum;
            float fmx = f; int imx = r;
            float fmn = f; int imn = r;
            #pragma unroll
            for (int off = 1; off < 32; off <<= 1) {
                const float px = __shfl_xor(fmx, off, 32); const int pix = __shfl_xor(imx, off, 32);
                const float qn = __shfl_xor(fmn, off, 32); const int qin = __shfl_xor(imn, off, 32);
                if (px > fmx || (px == fmx && pix < imx)) { fmx = px; imx = pix; }
                if (qn < fmn || (qn == fmn && qin < imn)) { fmn = qn; imn = qin; }
            }
            if (lane == 0)
                lds[12288 + n * 64 + t] = (fmx >= -fmn) ? (uint32_t)imx : (uint32_t)(NHALF + imn);
        }
    }
    __syncthreads();

    // ---- pack 4 bucket bytes -> dword (as rounds 2-13) ----
    if (tid < 64) {
        words[(size_t)bh * TT + t0 + tid] = lds[12288 + tid]
                                          | (lds[12288 + 64  + tid] << 8)
                                          | (lds[12288 + 128 + tid] << 16)
                                          | (lds[12288 + 192 + tid] << 24);
    }
}

// ---------------- Phase 2: materialize the [B,H,T,T] mask (int32 0/1) ----------------
// ROWS=32, 512-thread blocks (round-10 winner: P2 ~= 92 us, 5.8 TB/s).
#define ROWS 32
__device__ __forceinline__ uint32_t eq_any_byte(uint32_t a, uint32_t b) {
    const uint32_t x = a ^ b;
    return ((x - 0x01010101u) & ~x & 0x80808080u) ? 1u : 0u;
}

__global__ __launch_bounds__(512) void lsh_mask_kernel(
    const uint32_t* __restrict__ words,  // [BB*HH*TT]
    uint4* __restrict__ out)             // [BB*HH*TT][TT/4]
{
    const int bh  = blockIdx.x >> 6;            // TT/ROWS = 64 blocks per bh
    const int i0  = (blockIdx.x & 63) * ROWS;
    const int tid = threadIdx.x;                // 0..511, one uint4 of wj
    const uint32_t* wrow = words + (bh << 11);

    const uint4 wj = ((const uint4*)wrow)[tid];

    uint4* op = out + (((size_t)((bh << 11) + i0)) << 9) + tid;
    #pragma unroll
    for (int k = 0; k < ROWS; ++k) {
        const uint32_t wi = wrow[i0 + k];
        uint4 r;
        r.x = eq_any_byte(wi, wj.x); r.y = eq_any_byte(wi, wj.y);
        r.z = eq_any_byte(wi, wj.z); r.w = eq_any_byte(wi, wj.w);
        op[(size_t)k << 9] = r;
    }
}

extern "C" void kernel_launch(void* const* d_in, const int* in_sizes, int n_in,
                              void* d_out, int out_size, void* d_ws, size_t ws_size,
                              hipStream_t stream) {
    const float* hs  = (const float*)d_in[0];   // [2, 2048, 1024] f32
    const float* rot = (const float*)d_in[1];   // [16, 64, 4, 32] f32
    uint32_t* words  = (uint32_t*)d_ws;         // needs BB*HH*TT*4 = 256 KiB

    lsh_buckets_kernel<<<BB * HH * (TT / 64), 256, 0, stream>>>(hs, rot, words);
    lsh_mask_kernel<<<BB * HH * (TT / ROWS), 512, 0, stream>>>(words, (uint4*)d_out);
}

// Round 15
// 126.683 us; speedup vs baseline: 1.0278x; 1.0278x over previous
//
#include <hip/hip_runtime.h>
#include <stdint.h>

#define BB 2
#define HH 16
#define TT 2048
#define DD 64
#define NHASH 4
#define NHALF 32   // num_buckets/2

// ---------------- Phase 1: compute packed bucket words ----------------
// (round-6 kernel — best of 6 P1 variants tested; P1 ~= 30 us busy.
//  f64 accumulation + f32 compare + first-index tie-break: absmax 0 in
//  rounds 2-14. Dword pack via LDS — byte global stores regressed (r7/r12);
//  shuffle-butterfly epilogues regressed (r12/r14); f32 K-loop not faster (r14).)
__global__ __launch_bounds__(256, 3) void lsh_buckets_kernel(
    const float* __restrict__ hs,    // [BB, TT, HH*DD]
    const float* __restrict__ rot,   // [HH, DD, NHASH, NHALF]
    uint32_t* __restrict__ words)    // [BB*HH*TT]
{
    __shared__ uint32_t lds[12288];            // 48 KiB
    float4* v4 = (float4*)lds;                 // [64 t][16 slots]   (16 KiB)
    float4* r4 = (float4*)(lds + 4096);        // [4 n][32 r][16 slots] (32 KiB)

    const int blk  = blockIdx.x;
    const int bh   = blk >> 5;        // / (TT/64)
    const int tblk = blk & 31;
    const int b    = bh >> 4;
    const int h    = bh & 15;
    const int t0   = tblk * 64;
    const int tid  = threadIdx.x;
    const int n    = tid >> 6;        // wave = hash
    const int lane = tid & 63;
    const int tg   = lane >> 3;       // token group (8 tokens)
    const int rg   = lane & 7;        // r group (4 r's)

    // ---- stage v tile: [64 t][64 d] f32, slot = d4 ^ (t>>3) ----
    #pragma unroll
    for (int p = 0; p < 4; ++p) {
        const int k  = tid + p * 256;       // 0..1023 float4s
        const int t  = k >> 4;
        const int d4 = k & 15;
        const float4 f = ((const float4*)(hs + ((size_t)(b * TT + t0 + t)) * (HH * DD) + h * DD))[d4];
        v4[t * 16 + (d4 ^ (t >> 3))] = f;
    }
    // ---- stage rot: [4 n][32 r][64 d] f32, slot = d4 ^ (r>>2) ----
    {
        const float* rh = rot + (size_t)h * (DD * NHASH * NHALF);
        float* rf = (float*)r4;
        #pragma unroll
        for (int p = 0; p < 32; ++p) {
            const int g  = tid + p * 256;   // global idx: d*128 + n*32 + r (coalesced)
            const int d  = g >> 7;
            const int nr = g & 127;
            const int nn = nr >> 5;
            const int r  = nr & 31;
            const int slot = (d >> 2) ^ (r >> 2);
            rf[((nn * 32 + r) * 16 + slot) * 4 + (d & 3)] = rh[g];
        }
    }
    __syncthreads();

    // ---- K loop: acc[i][j] (t = tg*8+i, r = rg*4+j), f64 ----
    double acc[8][4];
    #pragma unroll
    for (int i = 0; i < 8; ++i)
        #pragma unroll
        for (int j = 0; j < 4; ++j) acc[i][j] = 0.0;

    const int vbase = tg * 8 * 16;                 // float4 index of first own token row
    const int rbase = (n * 32 + rg * 4) * 16;      // float4 index of first own r row

    for (int s = 0; s < 16; ++s) {                 // d = s*4 .. s*4+3
        double rd[4][4];
        #pragma unroll
        for (int j = 0; j < 4; ++j) {
            const float4 rf = r4[rbase + j * 16 + (s ^ rg)];
            rd[j][0] = (double)rf.x; rd[j][1] = (double)rf.y;
            rd[j][2] = (double)rf.z; rd[j][3] = (double)rf.w;
        }
        #pragma unroll
        for (int i = 0; i < 8; ++i) {
            const float4 vf = v4[vbase + i * 16 + (s ^ tg)];
            const double v0 = (double)vf.x, v1 = (double)vf.y;
            const double v2 = (double)vf.z, v3 = (double)vf.w;
            #pragma unroll
            for (int j = 0; j < 4; ++j) {
                acc[i][j] += v0 * rd[j][0];
                acc[i][j] += v1 * rd[j][1];
                acc[i][j] += v2 * rd[j][2];
                acc[i][j] += v3 * rd[j][3];
            }
        }
    }

    // ---- epilogue: argmax/argmin over r per (n,t) ----
    __syncthreads();   // all LDS reads done; alias lds for partials
    float*    vmaxL = (float*)lds;            // [4][64][9]
    float*    vminL = (float*)(lds + 2304);
    uint32_t* imaxL = lds + 4608;
    uint32_t* iminL = lds + 6912;
    uint32_t* bkt   = lds + 9216;             // [4][64]

    #pragma unroll
    for (int i = 0; i < 8; ++i) {
        const int t = tg * 8 + i;
        float fmx = -INFINITY; int imx = 0;
        float fmn =  INFINITY; int imn = 0;
        #pragma unroll
        for (int j = 0; j < 4; ++j) {
            const float f = (float)acc[i][j];
            const int   r = rg * 4 + j;
            if (f > fmx) { fmx = f; imx = r; }
            if (f < fmn) { fmn = f; imn = r; }
        }
        const int o = (n * 64 + t) * 9 + rg;
        vmaxL[o] = fmx; vminL[o] = fmn;
        imaxL[o] = (uint32_t)imx; iminL[o] = (uint32_t)imn;
    }
    __syncthreads();
    {
        const int nn = tid >> 6;
        const int t  = tid & 63;
        float fmx = -INFINITY; int imx = 0;
        float fmn =  INFINITY; int imn = 0;
        #pragma unroll
        for (int g = 0; g < 8; ++g) {     // rg ascending -> r ascending: first-index tie-break
            const int o = (nn * 64 + t) * 9 + g;
            const float fx = vmaxL[o];
            const float fn = vminL[o];
            if (fx > fmx) { fmx = fx; imx = (int)imaxL[o]; }
            if (fn < fmn) { fmn = fn; imn = (int)iminL[o]; }
        }
        const uint32_t bucket = (fmx >= -fmn) ? (uint32_t)imx : (uint32_t)(NHALF + imn);
        bkt[nn * 64 + t] = bucket;
    }
    __syncthreads();
    if (tid < 64) {
        words[(size_t)bh * TT + t0 + tid] = bkt[tid]
                                          | (bkt[64  + tid] << 8)
                                          | (bkt[128 + tid] << 16)
                                          | (bkt[192 + tid] << 24);
    }
}

// ---------------- Phase 2: materialize the [B,H,T,T] mask (int32 0/1) ----------------
// ROWS=32, 512-thread blocks (round-10 winner: P2 ~= 92 us, 5.8 TB/s;
// beat ROWS=8/ROWS=64/NT-store variants).
#define ROWS 32
__device__ __forceinline__ uint32_t eq_any_byte(uint32_t a, uint32_t b) {
    const uint32_t x = a ^ b;
    return ((x - 0x01010101u) & ~x & 0x80808080u) ? 1u : 0u;
}

__global__ __launch_bounds__(512) void lsh_mask_kernel(
    const uint32_t* __restrict__ words,  // [BB*HH*TT]
    uint4* __restrict__ out)             // [BB*HH*TT][TT/4]
{
    const int bh  = blockIdx.x >> 6;            // TT/ROWS = 64 blocks per bh
    const int i0  = (blockIdx.x & 63) * ROWS;
    const int tid = threadIdx.x;                // 0..511, one uint4 of wj
    const uint32_t* wrow = words + (bh << 11);

    const uint4 wj = ((const uint4*)wrow)[tid];

    uint4* op = out + (((size_t)((bh << 11) + i0)) << 9) + tid;
    #pragma unroll
    for (int k = 0; k < ROWS; ++k) {
        const uint32_t wi = wrow[i0 + k];
        uint4 r;
        r.x = eq_any_byte(wi, wj.x); r.y = eq_any_byte(wi, wj.y);
        r.z = eq_any_byte(wi, wj.z); r.w = eq_any_byte(wi, wj.w);
        op[(size_t)k << 9] = r;
    }
}

extern "C" void kernel_launch(void* const* d_in, const int* in_sizes, int n_in,
                              void* d_out, int out_size, void* d_ws, size_t ws_size,
                              hipStream_t stream) {
    const float* hs  = (const float*)d_in[0];   // [2, 2048, 1024] f32
    const float* rot = (const float*)d_in[1];   // [16, 64, 4, 32] f32
    uint32_t* words  = (uint32_t*)d_ws;         // needs BB*HH*TT*4 = 256 KiB

    lsh_buckets_kernel<<<BB * HH * (TT / 64), 256, 0, stream>>>(hs, rot, words);
    lsh_mask_kernel<<<BB * HH * (TT / ROWS), 512, 0, stream>>>(words, (uint4*)d_out);
}